// Round 26
// baseline (208.714 us; speedup 1.0000x reference)
//
#include <hip/hip_runtime.h>
#include <hip/hip_bf16.h>

typedef unsigned short u16;
typedef float f32x4 __attribute__((ext_vector_type(4)));
typedef float f32x16 __attribute__((ext_vector_type(16)));
typedef __bf16 bf16x4 __attribute__((ext_vector_type(4)));
typedef __bf16 bf16x8 __attribute__((ext_vector_type(8)));
typedef _Float16 half4 __attribute__((ext_vector_type(4)));
typedef _Float16 half8 __attribute__((ext_vector_type(8)));
typedef u16 u16x4 __attribute__((ext_vector_type(4)));
typedef u16 u16x8 __attribute__((ext_vector_type(8)));

#define NPIX 4096
#define CDIM 512
#define LOG2E 1.4426950408889634f

static __device__ __forceinline__ u16 f2bf(float f) {
  return __builtin_bit_cast(u16, (__bf16)f);
}
static __device__ __forceinline__ float bf2f(u16 u) {
  unsigned int v = ((unsigned int)u) << 16;
  return __builtin_bit_cast(float, v);
}
static __device__ __forceinline__ u16 f2h(float f) {
  return __builtin_bit_cast(u16, (_Float16)f);
}
static __device__ __forceinline__ f32x16 zero16() {
  f32x16 z;
#pragma unroll
  for (int i = 0; i < 16; ++i) z[i] = 0.0f;
  return z;
}
static __device__ __forceinline__ f32x16 mfma_bf(bf16x8 a, bf16x8 b, f32x16 c) {
  return __builtin_amdgcn_mfma_f32_32x32x16_bf16(a, b, c, 0, 0, 0);
}
static __device__ __forceinline__ f32x16 mfma_h32(half8 a, half8 b, f32x16 c) {
  return __builtin_amdgcn_mfma_f32_32x32x16_f16(a, b, c, 0, 0, 0);
}
static __device__ __forceinline__ bf16x8 b8(bf16x4 a, bf16x4 b) {
  bf16x8 r;
#pragma unroll
  for (int i = 0; i < 4; ++i) { r[i] = a[i]; r[4 + i] = b[i]; }
  return r;
}

// ---------------------------------------------------------------------------
// Kernel 0: W -> fp16 once (R23-R25 validated).
// ---------------------------------------------------------------------------
__global__ __launch_bounds__(256) void wconv_kernel(
    const float* __restrict__ Wq, const float* __restrict__ Wk,
    const float* __restrict__ Wv, u16* __restrict__ wf)
{
  int i = blockIdx.x * 256 + threadIdx.x;   // 0 .. 327679
  const float* src = (i < 64 * 512) ? (Wq + i)
                   : (i < 128 * 512) ? (Wk + (i - 64 * 512))
                                     : (Wv + (i - 128 * 512));
  wf[i] = f2h(*src);
}

// ---------------------------------------------------------------------------
// Kernel 1: fused QKV projection — byte-identical to R23-R25 (measured best).
// ---------------------------------------------------------------------------
__global__ __launch_bounds__(640, 2) void proj_kernel(
    const float* __restrict__ x, const u16* __restrict__ wf,
    const float* __restrict__ bq, const float* __restrict__ bk,
    const float* __restrict__ bv,
    u16* __restrict__ qh, u16* __restrict__ kh, u16* __restrict__ vv)
{
  const int b = blockIdx.y;
  const int rz = blockIdx.z;          // row-half: rows rz*320 .. rz*320+319
  const int nbase = blockIdx.x * 64;
  const int tid = threadIdx.x;
  const int w = tid >> 6;             // 10 waves; wave = 32 output rows
  const int lane = tid & 63;
  const int lhi = lane >> 5, llo = lane & 31;
  const int rowbase = rz * 320 + w * 32;

  __shared__ u16 xs[64 * 260];        // [n][k-half] fp16, stride 260, 33.3 KB

  const float* xb = x + (size_t)b * CDIM * NPIX + nbase;
  const u16* wrow = wf + (size_t)(rowbase + llo) * 512;

  f32x16 acc0 = zero16(), acc1 = zero16();

  for (int kh2 = 0; kh2 < 2; ++kh2) {
    __syncthreads();
    if (tid < 512) {
      int r = tid >> 4;            // 0..31
      int ci = (tid & 15) << 2;    // 0..60
#pragma unroll
      for (int it = 0; it < 8; ++it) {
        int krow = it * 32 + r;    // 0..255 within half
        f32x4 v4 = __builtin_nontemporal_load(
            (const f32x4*)&xb[(size_t)(kh2 * 256 + krow) * NPIX + ci]);
#pragma unroll
        for (int d = 0; d < 4; ++d) xs[(ci + d) * 260 + krow] = f2h(v4[d]);
      }
    }
    __syncthreads();

#pragma unroll 4
    for (int ks = 0; ks < 16; ++ks) {
      half8 af = *(const half8*)(wrow + kh2 * 256 + ks * 16 + 8 * lhi);
      const char* xk = (const char*)xs + (ks * 16 + 8 * lhi) * 2;
      half4 x00 = *(const half4*)(xk + (size_t)llo * 520);
      half4 x01 = *(const half4*)(xk + (size_t)llo * 520 + 8);
      half4 x10 = *(const half4*)(xk + (size_t)(32 + llo) * 520);
      half4 x11 = *(const half4*)(xk + (size_t)(32 + llo) * 520 + 8);
      half8 b0, b1;
#pragma unroll
      for (int j = 0; j < 4; ++j) {
        b0[j] = x00[j]; b0[4 + j] = x01[j];
        b1[j] = x10[j]; b1[4 + j] = x11[j];
      }
      acc0 = mfma_h32(af, b0, acc0);
      acc1 = mfma_h32(af, b1, acc1);
    }
  }

  const int type = rowbase >> 5;   // {0,1}: q; {2,3}: k; else v
#pragma unroll
  for (int cb = 0; cb < 2; ++cb) {
    const f32x16& acc = cb ? acc1 : acc0;
    const int n = nbase + 32 * cb + llo;
    if (type < 2) {       // q: fp16, log2e-scaled, [b][n][64]
#pragma unroll
      for (int gq = 0; gq < 4; ++gq) {
        int dr0 = 8 * gq + 4 * lhi;
        u16x4 hq;
#pragma unroll
        for (int jj = 0; jj < 4; ++jj) {
          float v = acc[4 * gq + jj] + bq[rowbase + dr0 + jj];
          hq[jj] = f2h(v * LOG2E);
        }
        *(u16x4*)(qh + ((size_t)b * NPIX + n) * 64 + rowbase + dr0) = hq;
      }
    } else if (type < 4) {  // k: fp16, fragment layout
      const int base = rowbase - 64;  // 0 or 32
      const int T = n >> 7, kq = (n >> 5) & 3, lf = n & 31;
#pragma unroll
      for (int gq = 0; gq < 4; ++gq) {
        int dr0 = 8 * gq + 4 * lhi;
        u16x4 hk;
#pragma unroll
        for (int jj = 0; jj < 4; ++jj)
          hk[jj] = f2h(acc[4 * gq + jj] + bk[base + dr0 + jj]);
        int sf = (base >> 4) + (gq >> 1);
        int lh = gq & 1;
        size_t F = (((size_t)b * 32 + T) * 4 + kq) * 4 + sf;
        *(u16x4*)(kh + F * 512 + (32 * lh + lf) * 8 + 4 * lhi) = hk;
      }
    } else {              // v: bf16, fragment layout
      const int T = n >> 7, s = (n >> 4) & 7, lh = (n >> 3) & 1, jn = n & 7;
#pragma unroll
      for (int gq = 0; gq < 4; ++gq) {
        int dr0 = 8 * gq + 4 * lhi;
#pragma unroll
        for (int jj = 0; jj < 4; ++jj) {
          int c = rowbase - 128 + dr0 + jj;
          float v = acc[4 * gq + jj] + bv[c];
          size_t F = ((((size_t)b * 2 + (c >> 8)) * 8 + ((c >> 5) & 7)) * 32 + T) * 8 + s;
          vv[F * 512 + (32 * lh + (c & 31)) * 8 + jn] = f2bf(v);
        }
      }
    }
  }
}

// ---------------------------------------------------------------------------
// Kernel 2: attention in 256-THREAD BLOCKS — the only block size the
// dispatcher co-schedules (R11: ~3.6 blocks/CU measured). Barriers now sync
// 4 waves (not 16), and independent co-resident blocks fill each other's
// latency gaps. Block = 32 q x 128 ch; grid 2048 = 128 qt x 4 b x 4 chq,
// XCD-swizzled (2 (b,chq) combos per XCD -> V 2MB + K 0.5MB L2-resident).
// Per 128-key tile: wave w builds S quadrant [32q x 32k(block w)] (q from
// LDS, K streamed 2 frags at a time), writes P (264B stride, 2-way); then
// PV: 8 MFMAs on its 32-ch slice, V streamed 2 frags at a time from global.
// Register budget fits 64 VGPRs: acc 16 + l 16 + transient sacc/kf/vf.
// S duplicated x4 by the chq split (+26 GF; MFMA pipe has 72% headroom).
// ---------------------------------------------------------------------------
__global__ __launch_bounds__(256) void attn_kernel(
    const u16* __restrict__ qh, const u16* __restrict__ kh,
    const u16* __restrict__ vv,
    const float* __restrict__ x, const float* __restrict__ gamma,
    float* __restrict__ out)
{
  const int bid = blockIdx.x;
  const int sw = ((bid & 7) << 8) | (bid >> 3);  // bijective, 2048 = 8*256
  const int combo = sw >> 7;          // 0..15 = (batch, chq)
  const int batch = combo >> 2;
  const int chq = combo & 3;          // 128-ch quarter
  const int qbase = (sw & 127) * 32;
  const int tid = threadIdx.x;
  const int w = tid >> 6;             // 4 waves
  const int lane = tid & 63;
  const int lhi = lane >> 5, llo = lane & 31;

  __shared__ alignas(16) char Ps[8448];    // [32 rows x 264 B] bf16
  __shared__ alignas(16) char Qs[4096];    // [d8 0..7][32 q] x 16 B
  __shared__ float lred[32][4];
  __shared__ alignas(16) float rl_lds[32];

  // V fragment channel-block index for this wave's 32-ch slice.
  const int vcb = (batch * 2 + (chq >> 1)) * 8 + (chq & 1) * 4 + w;

  f32x16 acc0 = zero16();
  float l_part[16];
#pragma unroll
  for (int r = 0; r < 16; ++r) l_part[r] = 0.0f;

  // Prologue: stage q rows qbase..qbase+31 (fp16, slot-major), one u16x8/thr.
  {
    int d8 = tid & 7, row = tid >> 3;   // row 0..31
    *(u16x8*)(Qs + d8 * 512 + row * 16) =
        *(const u16x8*)(qh + ((size_t)batch * NPIX + qbase + row) * 64 + d8 * 8);
  }
  __syncthreads();

  for (int t = 0; t < 32; ++t) {
    // --- S: quadrant [32q x 32k(block w)] of 128-key tile t. ---
    {
      size_t F = (((size_t)batch * 32 + t) * 4 + w) * 4;
      const u16* kp = kh + F * 512 + (size_t)lane * 8;
      f32x16 sacc = zero16();
#pragma unroll
      for (int sp = 0; sp < 2; ++sp) {
        half8 k0 = *(const half8*)(kp + (2 * sp) * 512);
        half8 k1 = *(const half8*)(kp + (2 * sp + 1) * 512);
        half8 q0 = *(const half8*)(Qs + (4 * sp + lhi) * 512 + llo * 16);
        half8 q1 = *(const half8*)(Qs + (4 * sp + 2 + lhi) * 512 + llo * 16);
        sacc = mfma_h32(q0, k0, sacc);
        sacc = mfma_h32(q1, k1, sacc);
      }
#pragma unroll
      for (int r = 0; r < 16; ++r) {
        float p = __builtin_amdgcn_exp2f(sacc[r]);
        u16 pb = f2bf(p);
        l_part[r] += bf2f(pb);
        int row = (r & 3) + 8 * (r >> 2) + 4 * lhi;
        *(u16*)(Ps + row * 264 + (w * 32 + llo) * 2) = pb;
      }
    }
    __syncthreads();
    // --- PV: 8 k-steps over tile t, V streamed 2 frags at a time. ---
    {
      const char* pr = Ps + llo * 264 + 16 * lhi;
      const u16* g = vv + ((size_t)vcb * 32 + t) * 8 * 512 + (size_t)lane * 8;
      __builtin_amdgcn_s_setprio(1);
#pragma unroll
      for (int k2 = 0; k2 < 4; ++k2) {
        bf16x8 v0 = *(const bf16x8*)(g + (2 * k2) * 512);
        bf16x8 v1 = *(const bf16x8*)(g + (2 * k2 + 1) * 512);
        bf16x4 a0 = *(const bf16x4*)(pr + 32 * (2 * k2));
        bf16x4 a1 = *(const bf16x4*)(pr + 32 * (2 * k2) + 8);
        bf16x4 c0 = *(const bf16x4*)(pr + 32 * (2 * k2 + 1));
        bf16x4 c1 = *(const bf16x4*)(pr + 32 * (2 * k2 + 1) + 8);
        acc0 = mfma_bf(b8(a0, a1), v0, acc0);
        acc0 = mfma_bf(b8(c0, c1), v1, acc0);
      }
      __builtin_amdgcn_s_setprio(0);
    }
    __syncthreads();
  }

  // l reduction: butterfly over the 32 key-lanes, merge 4 key-blocks in LDS.
#pragma unroll
  for (int d = 1; d < 32; d <<= 1)
#pragma unroll
    for (int r = 0; r < 16; ++r) l_part[r] += __shfl_xor(l_part[r], d, 64);
  if (llo == 0) {
#pragma unroll
    for (int r = 0; r < 16; ++r) {
      int row = (r & 3) + 8 * (r >> 2) + 4 * lhi;
      lred[row][w] = l_part[r];
    }
  }
  __syncthreads();
  if (tid < 32)
    rl_lds[tid] = 1.0f / (lred[tid][0] + lred[tid][1] + lred[tid][2] + lred[tid][3]);
  __syncthreads();

  // Epilogue: out = gamma * acc/l + x for this wave's 32 channels.
  {
    const float g = gamma[0];
    const int c = chq * 128 + w * 32 + llo;
#pragma unroll
    for (int gq = 0; gq < 4; ++gq) {
      int qrow = 8 * gq + 4 * lhi;
      size_t off = ((size_t)batch * CDIM + c) * NPIX + qbase + qrow;
      f32x4 xv = *(const f32x4*)(x + off);
      f32x4 rlv = *(const f32x4*)&rl_lds[qrow];
      f32x4 ov;
#pragma unroll
      for (int jj = 0; jj < 4; ++jj)
        ov[jj] = g * acc0[4 * gq + jj] * rlv[jj] + xv[jj];
      *(f32x4*)(out + off) = ov;
    }
  }
}

extern "C" void kernel_launch(void* const* d_in, const int* in_sizes, int n_in,
                              void* d_out, int out_size, void* d_ws, size_t ws_size,
                              hipStream_t stream) {
  (void)in_sizes; (void)n_in; (void)out_size; (void)ws_size;
  const float* x     = (const float*)d_in[0];
  const float* Wq    = (const float*)d_in[1];
  const float* bq    = (const float*)d_in[2];
  const float* Wk    = (const float*)d_in[3];
  const float* bk    = (const float*)d_in[4];
  const float* Wv    = (const float*)d_in[5];
  const float* bv    = (const float*)d_in[6];
  const float* gamma = (const float*)d_in[7];
  float* out = (float*)d_out;

  // Workspace (bytes): q fp16 0..2M, k-frag fp16 2..4M, v-frag bf16 4..20M,
  // W fp16 20M..20.625M.
  char* ws = (char*)d_ws;
  u16* qh = (u16*)(ws);
  u16* kh = (u16*)(ws + (2u << 20));
  u16* vv = (u16*)(ws + (4u << 20));
  u16* wf = (u16*)(ws + (20u << 20));

  wconv_kernel<<<1280, 256, 0, stream>>>(Wq, Wk, Wv, wf);
  proj_kernel<<<dim3(64, 4, 2), 640, 0, stream>>>(x, wf, bq, bk, bv,
                                                  qh, kh, vv);
  attn_kernel<<<2048, 256, 0, stream>>>(qh, kh, vv, x, gamma, out);
}

// Round 27
// 164.427 us; speedup vs baseline: 1.2693x; 1.2693x over previous
//
#include <hip/hip_runtime.h>
#include <hip/hip_bf16.h>

typedef unsigned short u16;
typedef float f32x4 __attribute__((ext_vector_type(4)));
typedef float f32x16 __attribute__((ext_vector_type(16)));
typedef __bf16 bf16x4 __attribute__((ext_vector_type(4)));
typedef __bf16 bf16x8 __attribute__((ext_vector_type(8)));
typedef _Float16 half4 __attribute__((ext_vector_type(4)));
typedef _Float16 half8 __attribute__((ext_vector_type(8)));
typedef u16 u16x4 __attribute__((ext_vector_type(4)));
typedef u16 u16x8 __attribute__((ext_vector_type(8)));

#define NPIX 4096
#define CDIM 512
#define LOG2E 1.4426950408889634f

static __device__ __forceinline__ u16 f2bf(float f) {
  return __builtin_bit_cast(u16, (__bf16)f);
}
static __device__ __forceinline__ float bf2f(u16 u) {
  unsigned int v = ((unsigned int)u) << 16;
  return __builtin_bit_cast(float, v);
}
static __device__ __forceinline__ u16 f2h(float f) {
  return __builtin_bit_cast(u16, (_Float16)f);
}
static __device__ __forceinline__ f32x16 zero16() {
  f32x16 z;
#pragma unroll
  for (int i = 0; i < 16; ++i) z[i] = 0.0f;
  return z;
}
static __device__ __forceinline__ f32x16 mfma_bf(bf16x8 a, bf16x8 b, f32x16 c) {
  return __builtin_amdgcn_mfma_f32_32x32x16_bf16(a, b, c, 0, 0, 0);
}
static __device__ __forceinline__ f32x16 mfma_h32(half8 a, half8 b, f32x16 c) {
  return __builtin_amdgcn_mfma_f32_32x32x16_f16(a, b, c, 0, 0, 0);
}
static __device__ __forceinline__ half8 h8(half4 a, half4 b) {
  half8 r;
#pragma unroll
  for (int i = 0; i < 4; ++i) { r[i] = a[i]; r[4 + i] = b[i]; }
  return r;
}
static __device__ __forceinline__ bf16x8 b8(bf16x4 a, bf16x4 b) {
  bf16x8 r;
#pragma unroll
  for (int i = 0; i < 4; ++i) { r[i] = a[i]; r[4 + i] = b[i]; }
  return r;
}

// ---------------------------------------------------------------------------
// Kernel 0: W -> fp16 once (R23-R25 validated).
// ---------------------------------------------------------------------------
__global__ __launch_bounds__(256) void wconv_kernel(
    const float* __restrict__ Wq, const float* __restrict__ Wk,
    const float* __restrict__ Wv, u16* __restrict__ wf)
{
  int i = blockIdx.x * 256 + threadIdx.x;   // 0 .. 327679
  const float* src = (i < 64 * 512) ? (Wq + i)
                   : (i < 128 * 512) ? (Wk + (i - 64 * 512))
                                     : (Wv + (i - 128 * 512));
  wf[i] = f2h(*src);
}

// ---------------------------------------------------------------------------
// Kernel 1: fused QKV projection — byte-identical to R23-R25 (measured best).
// ---------------------------------------------------------------------------
__global__ __launch_bounds__(640, 2) void proj_kernel(
    const float* __restrict__ x, const u16* __restrict__ wf,
    const float* __restrict__ bq, const float* __restrict__ bk,
    const float* __restrict__ bv,
    u16* __restrict__ qh, u16* __restrict__ kh, u16* __restrict__ vv)
{
  const int b = blockIdx.y;
  const int rz = blockIdx.z;          // row-half: rows rz*320 .. rz*320+319
  const int nbase = blockIdx.x * 64;
  const int tid = threadIdx.x;
  const int w = tid >> 6;             // 10 waves; wave = 32 output rows
  const int lane = tid & 63;
  const int lhi = lane >> 5, llo = lane & 31;
  const int rowbase = rz * 320 + w * 32;

  __shared__ u16 xs[64 * 260];        // [n][k-half] fp16, stride 260, 33.3 KB

  const float* xb = x + (size_t)b * CDIM * NPIX + nbase;
  const u16* wrow = wf + (size_t)(rowbase + llo) * 512;

  f32x16 acc0 = zero16(), acc1 = zero16();

  for (int kh2 = 0; kh2 < 2; ++kh2) {
    __syncthreads();
    if (tid < 512) {
      int r = tid >> 4;            // 0..31
      int ci = (tid & 15) << 2;    // 0..60
#pragma unroll
      for (int it = 0; it < 8; ++it) {
        int krow = it * 32 + r;    // 0..255 within half
        f32x4 v4 = __builtin_nontemporal_load(
            (const f32x4*)&xb[(size_t)(kh2 * 256 + krow) * NPIX + ci]);
#pragma unroll
        for (int d = 0; d < 4; ++d) xs[(ci + d) * 260 + krow] = f2h(v4[d]);
      }
    }
    __syncthreads();

#pragma unroll 4
    for (int ks = 0; ks < 16; ++ks) {
      half8 af = *(const half8*)(wrow + kh2 * 256 + ks * 16 + 8 * lhi);
      const char* xk = (const char*)xs + (ks * 16 + 8 * lhi) * 2;
      half4 x00 = *(const half4*)(xk + (size_t)llo * 520);
      half4 x01 = *(const half4*)(xk + (size_t)llo * 520 + 8);
      half4 x10 = *(const half4*)(xk + (size_t)(32 + llo) * 520);
      half4 x11 = *(const half4*)(xk + (size_t)(32 + llo) * 520 + 8);
      acc0 = mfma_h32(af, h8(x00, x01), acc0);
      acc1 = mfma_h32(af, h8(x10, x11), acc1);
    }
  }

  const int type = rowbase >> 5;   // {0,1}: q; {2,3}: k; else v
#pragma unroll
  for (int cb = 0; cb < 2; ++cb) {
    const f32x16& acc = cb ? acc1 : acc0;
    const int n = nbase + 32 * cb + llo;
    if (type < 2) {       // q: fp16, log2e-scaled, [b][n][64]
#pragma unroll
      for (int gq = 0; gq < 4; ++gq) {
        int dr0 = 8 * gq + 4 * lhi;
        u16x4 hq;
#pragma unroll
        for (int jj = 0; jj < 4; ++jj) {
          float v = acc[4 * gq + jj] + bq[rowbase + dr0 + jj];
          hq[jj] = f2h(v * LOG2E);
        }
        *(u16x4*)(qh + ((size_t)b * NPIX + n) * 64 + rowbase + dr0) = hq;
      }
    } else if (type < 4) {  // k: fp16, fragment layout
      const int base = rowbase - 64;  // 0 or 32
      const int T = n >> 7, kq = (n >> 5) & 3, lf = n & 31;
#pragma unroll
      for (int gq = 0; gq < 4; ++gq) {
        int dr0 = 8 * gq + 4 * lhi;
        u16x4 hk;
#pragma unroll
        for (int jj = 0; jj < 4; ++jj)
          hk[jj] = f2h(acc[4 * gq + jj] + bk[base + dr0 + jj]);
        int sf = (base >> 4) + (gq >> 1);
        int lh = gq & 1;
        size_t F = (((size_t)b * 32 + T) * 4 + kq) * 4 + sf;
        *(u16x4*)(kh + F * 512 + (32 * lh + lf) * 8 + 4 * lhi) = hk;
      }
    } else {              // v: bf16, fragment layout
      const int T = n >> 7, s = (n >> 4) & 7, lh = (n >> 3) & 1, jn = n & 7;
#pragma unroll
      for (int gq = 0; gq < 4; ++gq) {
        int dr0 = 8 * gq + 4 * lhi;
#pragma unroll
        for (int jj = 0; jj < 4; ++jj) {
          int c = rowbase - 128 + dr0 + jj;
          float v = acc[4 * gq + jj] + bv[c];
          size_t F = ((((size_t)b * 2 + (c >> 8)) * 8 + ((c >> 5) & 7)) * 32 + T) * 8 + s;
          vv[F * 512 + (32 * lh + (c & 31)) * 8 + jn] = f2bf(v);
        }
      }
    }
  }
}

// ---------------------------------------------------------------------------
// Kernel 2: attention — byte-identical to R25 (the measured best: 128-key
// tiles, 32 phases, 8 PV + 2x4 S groups, P dbuf @ 264 B stride, V direct
// from global in fragment layout, setprio on PV MFMAs).
// ---------------------------------------------------------------------------

#define LOADK(T, J) do {                                                      \
  size_t F_ = (((size_t)batch * 32 + (size_t)(T)) * 4 + (J)) * 4;             \
  const u16* kp_ = kh + F_ * 512 + (size_t)lane * 8;                          \
  _Pragma("unroll") for (int s_ = 0; s_ < 4; ++s_)                            \
    kf[s_] = *(const half8*)(kp_ + s_ * 512);                                 \
} while (0)

#define S_PHASE(PB, J) do {                                                   \
  f32x16 sacc_ = zero16();                                                    \
  _Pragma("unroll") for (int s_ = 0; s_ < 4; ++s_) {                          \
    half8 qf_ = *(const half8*)(Qs + (2 * s_ + lhi) * 1024                    \
                                + (32 * rb_s + llo) * 16);                    \
    sacc_ = mfma_h32(qf_, kf[s_], sacc_);                                     \
  }                                                                           \
  _Pragma("unroll") for (int r_ = 0; r_ < 16; ++r_) {                         \
    float p_ = __builtin_amdgcn_exp2f(sacc_[r_]);                             \
    u16 pb_ = f2bf(p_);                                                       \
    l_part[r_] += bf2f(pb_);                                                  \
    int row_ = 32 * rb_s + (r_ & 3) + 8 * (r_ >> 2) + 4 * lhi;                \
    *(u16*)((PB) + row_ * 264 + ((J) * 32 + llo) * 2) = pb_;                  \
  }                                                                           \
} while (0)

// V subtile H (0: keys 0-63, 1: keys 64-127) of 128-key tile T, wave w.
#define PVLOADV(T, H) do {                                                    \
  size_t F0_ = (size_t)(bc8 + w) * 256 + (size_t)(T) * 8 + (H) * 4;           \
  const u16* g_ = vv + F0_ * 512 + (size_t)lane * 8;                          \
  vf[0] = *(const bf16x8*)(g_);                                               \
  vf[1] = *(const bf16x8*)(g_ + 512);                                         \
  vf[2] = *(const bf16x8*)(g_ + 1024);                                        \
  vf[3] = *(const bf16x8*)(g_ + 1536);                                        \
} while (0)

#define PV_PHASE(PB, H) do {                                                  \
  const char* pr_ = (PB) + llo * 264 + (H) * 128 + 16 * lhi;                  \
  __builtin_amdgcn_s_setprio(1);                                              \
  _Pragma("unroll") for (int s_ = 0; s_ < 4; ++s_) {                          \
    bf16x4 a0_ = *(const bf16x4*)(pr_ + 32 * s_);                             \
    bf16x4 a1_ = *(const bf16x4*)(pr_ + 32 * s_ + 8);                         \
    bf16x4 c0_ = *(const bf16x4*)(pr_ + 8448 + 32 * s_);                      \
    bf16x4 c1_ = *(const bf16x4*)(pr_ + 8448 + 32 * s_ + 8);                  \
    acc0 = mfma_bf(b8(a0_, a1_), vf[s_], acc0);                               \
    acc1 = mfma_bf(b8(c0_, c1_), vf[s_], acc1);                               \
  }                                                                           \
  __builtin_amdgcn_s_setprio(0);                                              \
} while (0)

__global__ __launch_bounds__(1024) void attn_kernel(
    const u16* __restrict__ qh, const u16* __restrict__ kh,
    const u16* __restrict__ vv,
    const float* __restrict__ x, const float* __restrict__ gamma,
    float* __restrict__ out)
{
  const int bid = blockIdx.x;
  const int sw = ((bid & 7) << 6) | (bid >> 3);  // bijective, 512 = 8*64
  const int batch = sw >> 7;
  const int chhalf = (sw >> 6) & 1;
  const int qbase = (sw & 63) * 64;
  const int tid = threadIdx.x;
  const int w = tid >> 6;             // 0-7 PV; 8-11 S grp0; 12-15 S grp1
  const int lane = tid & 63;
  const int lhi = lane >> 5, llo = lane & 31;
  const bool isPV = (w < 8);
  const int grp = (w >= 12) ? 1 : 0;
  const int swv = (w - 8) & 3;
  const int rb_s = swv & 1;           // S row half (q 0-31 / 32-63)
  const int kq2 = swv >> 1;           // S quadrant pair: blocks kq2, kq2+2
  const int jA = kq2, jB = kq2 + 2;   // 32-key blocks within 128-key tile
  const int bc8 = (batch * 2 + chhalf) * 8;

  __shared__ alignas(16) char Psm[33792];   // 2 x [64 rows x 264 B] bf16
  __shared__ alignas(16) char Qs[8192];     // [d8][64 q] x 16 B, slot-major
  __shared__ float lred[64][4];
  __shared__ alignas(16) float rl_lds[64];

  f32x16 acc0 = zero16(), acc1 = zero16();
  float l_part[16];
#pragma unroll
  for (int r = 0; r < 16; ++r) l_part[r] = 0.0f;
  half8 kf[4];
  bf16x8 vf[4];

  // Prologue A: grp0 fills Qs + prefetches K(tile1, jA); grp1 K(tile0, jA).
  if (!isPV) {
    if (grp == 0) {
#pragma unroll
      for (int j = 0; j < 2; ++j) {
        int idx = swv * 128 + j * 64 + lane;   // 0..511
        int d8 = idx & 7, row = idx >> 3;
        *(u16x8*)(Qs + d8 * 1024 + row * 16) =
            *(const u16x8*)(qh + ((size_t)batch * NPIX + qbase + row) * 64 + d8 * 8);
      }
      LOADK(1, jA);
    } else {
      LOADK(0, jA);
    }
  }
  __syncthreads();
  // Prologue B: grp1 builds tile 0 -> P[0]; prefetches K(tile2, jA).
  if (!isPV && grp == 1) {
    S_PHASE(Psm, jA);
    LOADK(0, jB);
    S_PHASE(Psm, jB);
    LOADK(2, jA);
  }
  __syncthreads();

  // Main loop (32 phases): phase t: PV consumes tile t from P[t&1] in two
  // halves; S group (t&1) builds tile t+1 into P[(t+1)&1], prefetches
  // K(t+3, jA).
  for (int t = 0; t < 32; ++t) {
    if (isPV) {
      PVLOADV(t, 0);
      PV_PHASE(Psm + (t & 1) * 16896, 0);
      PVLOADV(t, 1);
      PV_PHASE(Psm + (t & 1) * 16896, 1);
    } else if (grp == (t & 1)) {
      if (t + 1 < 32) {
        char* PB = Psm + ((t + 1) & 1) * 16896;
        S_PHASE(PB, jA);
        LOADK(t + 1, jB);
        S_PHASE(PB, jB);
        if (t + 3 < 32) LOADK(t + 3, jA);
      }
    }
    __syncthreads();
  }

  // l reduction: butterfly over 32 key-lanes; wave covers blocks jA+jB.
  if (!isPV) {
#pragma unroll
    for (int d = 1; d < 32; d <<= 1)
#pragma unroll
      for (int r = 0; r < 16; ++r) l_part[r] += __shfl_xor(l_part[r], d, 64);
    if (llo == 0) {
#pragma unroll
      for (int r = 0; r < 16; ++r) {
        int row = 32 * rb_s + (r & 3) + 8 * (r >> 2) + 4 * lhi;
        lred[row][2 * kq2 + grp] = l_part[r];
      }
    }
  }
  __syncthreads();
  if (tid < 64)
    rl_lds[tid] = 1.0f / (lred[tid][0] + lred[tid][1] + lred[tid][2] + lred[tid][3]);
  __syncthreads();

  // Epilogue (PV waves): out = gamma * acc/l + x.
  if (isPV) {
    const float g = gamma[0];
    const int c = chhalf * 256 + 32 * w + llo;
#pragma unroll
    for (int ab = 0; ab < 2; ++ab) {
      const f32x16& a = ab ? acc1 : acc0;
#pragma unroll
      for (int gq = 0; gq < 4; ++gq) {
        int qrow = 32 * ab + 8 * gq + 4 * lhi;
        size_t off = ((size_t)batch * CDIM + c) * NPIX + qbase + qrow;
        f32x4 xv = *(const f32x4*)(x + off);
        f32x4 rlv = *(const f32x4*)&rl_lds[qrow];
        f32x4 ov;
#pragma unroll
        for (int jj = 0; jj < 4; ++jj)
          ov[jj] = g * a[4 * gq + jj] * rlv[jj] + xv[jj];
        *(f32x4*)(out + off) = ov;
      }
    }
  }
}

extern "C" void kernel_launch(void* const* d_in, const int* in_sizes, int n_in,
                              void* d_out, int out_size, void* d_ws, size_t ws_size,
                              hipStream_t stream) {
  (void)in_sizes; (void)n_in; (void)out_size; (void)ws_size;
  const float* x     = (const float*)d_in[0];
  const float* Wq    = (const float*)d_in[1];
  const float* bq    = (const float*)d_in[2];
  const float* Wk    = (const float*)d_in[3];
  const float* bk    = (const float*)d_in[4];
  const float* Wv    = (const float*)d_in[5];
  const float* bv    = (const float*)d_in[6];
  const float* gamma = (const float*)d_in[7];
  float* out = (float*)d_out;

  // Workspace (bytes): q fp16 0..2M, k-frag fp16 2..4M, v-frag bf16 4..20M,
  // W fp16 20M..20.625M.
  char* ws = (char*)d_ws;
  u16* qh = (u16*)(ws);
  u16* kh = (u16*)(ws + (2u << 20));
  u16* vv = (u16*)(ws + (4u << 20));
  u16* wf = (u16*)(ws + (20u << 20));

  wconv_kernel<<<1280, 256, 0, stream>>>(Wq, Wk, Wv, wf);
  proj_kernel<<<dim3(64, 4, 2), 640, 0, stream>>>(x, wf, bq, bk, bv,
                                                  qh, kh, vv);
  attn_kernel<<<512, 1024, 0, stream>>>(qh, kh, vv, x, gamma, out);
}